// Round 8
// baseline (1059.674 us; speedup 1.0000x reference)
//
#include <hip/hip_runtime.h>
#include <hip/hip_cooperative_groups.h>

#define N_NODES 50000
#define N_EDGES 1600000
#define D_FEAT 512
#define FILTERS 256
#define NUM_CLASSES 16

typedef __bf16 bf16x8 __attribute__((ext_vector_type(8)));
typedef float f32x4 __attribute__((ext_vector_type(4)));
typedef _Float16 half4 __attribute__((ext_vector_type(4)));
typedef _Float16 f16x8 __attribute__((ext_vector_type(8)));

#define GLOAD_LDS16(g, l)                                                  \
  __builtin_amdgcn_global_load_lds(                                        \
      (const __attribute__((address_space(1))) unsigned int*)(g),          \
      (__attribute__((address_space(3))) unsigned int*)(l), 16, 0, 0)

// ---------------------------------------------------------------------------
// Fused CSR build + W1 split, ONE cooperative launch.
// r8 fix: 1024 blocks (262144 threads) so the edge phases have real
// parallelism (6 edges/thread, grid-stride); scan phases gated to the
// first 196 blocks. VGPR 12 / LDS 1KB -> 4 blocks/CU, co-residency safe.
// ---------------------------------------------------------------------------
#define CSR_NB 1024
#define SCAN_NB 196
__global__ __launch_bounds__(256) void csr_coop_kernel(
    const float* __restrict__ W1, __bf16* __restrict__ Wth,
    __bf16* __restrict__ Wtl, const int* __restrict__ esrc,
    const int* __restrict__ edst, const float* __restrict__ ew,
    int* __restrict__ deg, int* __restrict__ row_ptr,
    int* __restrict__ cursor, int* __restrict__ bsum,
    int4* __restrict__ meta) {
  cooperative_groups::grid_group grid = cooperative_groups::this_grid();
  const int tid = blockIdx.x * 256 + threadIdx.x;
  const int nthr = CSR_NB * 256;

  // P0: zero deg + split W1 [512,256] fp32 -> W1^T hi/lo bf16 [256,512]
  for (int i = tid; i < N_NODES; i += nthr) deg[i] = 0;
  for (int i = tid; i < D_FEAT * FILTERS; i += nthr) {
    const float v = W1[i];
    const int k = i >> 8;
    const int n = i & 255;
    const __bf16 h = (__bf16)v;
    Wth[n * D_FEAT + k] = h;
    Wtl[n * D_FEAT + k] = (__bf16)(v - (float)h);
  }
  grid.sync();

  // P1: degree histogram (grid-stride, full device)
  for (int e = tid; e < N_EDGES; e += nthr) atomicAdd(&deg[edst[e]], 1);
  grid.sync();

  // P2: per-block exclusive scan over nodes (first SCAN_NB blocks only)
  __shared__ int s[256];
  int excl = 0;
  if (blockIdx.x < SCAN_NB) {
    const int nid = blockIdx.x * 256 + threadIdx.x;
    const int v = (nid < N_NODES) ? deg[nid] : 0;
    s[threadIdx.x] = v;
    __syncthreads();
    for (int off = 1; off < 256; off <<= 1) {
      const int t = (threadIdx.x >= off) ? s[threadIdx.x - off] : 0;
      __syncthreads();
      s[threadIdx.x] += t;
      __syncthreads();
    }
    excl = s[threadIdx.x] - v;
    if (threadIdx.x == 255) bsum[blockIdx.x] = s[255];
  }
  grid.sync();

  // P3: block 0 scans the block sums
  if (blockIdx.x == 0) {
    const int bv = (threadIdx.x < SCAN_NB) ? bsum[threadIdx.x] : 0;
    s[threadIdx.x] = bv;
    __syncthreads();
    for (int off = 1; off < 256; off <<= 1) {
      const int t = (threadIdx.x >= off) ? s[threadIdx.x - off] : 0;
      __syncthreads();
      s[threadIdx.x] += t;
      __syncthreads();
    }
    if (threadIdx.x < SCAN_NB) bsum[threadIdx.x] = s[threadIdx.x] - bv;
  }
  grid.sync();

  // P4: add block offsets -> row_ptr, cursor
  if (blockIdx.x < SCAN_NB) {
    const int nid = blockIdx.x * 256 + threadIdx.x;
    if (nid < N_NODES) {
      const int r = excl + bsum[blockIdx.x];
      row_ptr[nid] = r;
      cursor[nid] = r;
    }
    if (nid == 0) row_ptr[N_NODES] = N_EDGES;
  }
  grid.sync();

  // P5: fill dst-sorted meta = (src, w_bits, dst, 0)
  for (int e = tid; e < N_EDGES; e += nthr) {
    const int d = edst[e];
    const int pos = atomicAdd(&cursor[d], 1);
    meta[pos] = make_int4(esrc[e], __float_as_int(ew[e]), d, 0);
  }
}

// ---------------------------------------------------------------------------
// GEMM1 via MFMA bf16x3: XW1 = X @ W1, fp32-accurate, output stored fp16
// row-major (r2-verified version).
// ---------------------------------------------------------------------------
__global__ __launch_bounds__(256) void gemm1_mfma_kernel(
    const float* __restrict__ A, const __bf16* __restrict__ Bh,
    const __bf16* __restrict__ Bl, _Float16* __restrict__ C) {
  const int K = D_FEAT;
  __shared__ __bf16 sAh[128 * 32];
  __shared__ __bf16 sAl[128 * 32];
  __shared__ __bf16 sBh[128 * 32];
  __shared__ __bf16 sBl[128 * 32];

  const int tid = threadIdx.x;
  const int wave = tid >> 6;
  const int lane = tid & 63;
  const int wm = (wave >> 1) * 64;
  const int wn = (wave & 1) * 64;
  const int m0 = blockIdx.x * 128;
  const int n0 = blockIdx.y * 128;

  const int arow = tid >> 1;
  const int aks = (tid & 1) * 16;
  int am = m0 + arow;
  if (am >= N_NODES) am = N_NODES - 1;
  const float* aptr = A + (size_t)am * K + aks;

  const int lr = lane >> 2;
  const int lc = (lane & 3) * 8;
  const int fm = lane & 15;
  const int fq = lane >> 4;

  f32x4 acc[4][4] = {};

  for (int k0 = 0; k0 < K; k0 += 32) {
    const float4* ap = (const float4*)(aptr + k0);
    const float4 a0 = ap[0], a1 = ap[1], a2 = ap[2], a3 = ap[3];

    __syncthreads();

#pragma unroll
    for (int i = 0; i < 2; ++i) {
      const int row = wave * 32 + i * 16;
      GLOAD_LDS16(Bh + (size_t)(n0 + row + lr) * K + k0 + lc, sBh + row * 32);
      GLOAD_LDS16(Bl + (size_t)(n0 + row + lr) * K + k0 + lc, sBl + row * 32);
    }

    float va[16] = {a0.x, a0.y, a0.z, a0.w, a1.x, a1.y, a1.z, a1.w,
                    a2.x, a2.y, a2.z, a2.w, a3.x, a3.y, a3.z, a3.w};
    __bf16 hh[16], ll[16];
#pragma unroll
    for (int i = 0; i < 16; ++i) {
      const __bf16 h = (__bf16)va[i];
      hh[i] = h;
      ll[i] = (__bf16)(va[i] - (float)h);
    }
    *(bf16x8*)(sAh + arow * 32 + aks) = *(bf16x8*)&hh[0];
    *(bf16x8*)(sAh + arow * 32 + aks + 8) = *(bf16x8*)&hh[8];
    *(bf16x8*)(sAl + arow * 32 + aks) = *(bf16x8*)&ll[0];
    *(bf16x8*)(sAl + arow * 32 + aks + 8) = *(bf16x8*)&ll[8];

    __syncthreads();

    bf16x8 fah[4], fal[4], fbh[4], fbl[4];
#pragma unroll
    for (int t = 0; t < 4; ++t) {
      const int moff = (wm + t * 16 + fm) * 32 + fq * 8;
      fah[t] = *(const bf16x8*)(sAh + moff);
      fal[t] = *(const bf16x8*)(sAl + moff);
      const int noff = (wn + t * 16 + fm) * 32 + fq * 8;
      fbh[t] = *(const bf16x8*)(sBh + noff);
      fbl[t] = *(const bf16x8*)(sBl + noff);
    }
#pragma unroll
    for (int i = 0; i < 4; ++i)
#pragma unroll
      for (int j = 0; j < 4; ++j)
        acc[i][j] = __builtin_amdgcn_mfma_f32_16x16x32_bf16(fah[i], fbh[j],
                                                            acc[i][j], 0, 0, 0);
#pragma unroll
    for (int i = 0; i < 4; ++i)
#pragma unroll
      for (int j = 0; j < 4; ++j)
        acc[i][j] = __builtin_amdgcn_mfma_f32_16x16x32_bf16(fah[i], fbl[j],
                                                            acc[i][j], 0, 0, 0);
#pragma unroll
    for (int i = 0; i < 4; ++i)
#pragma unroll
      for (int j = 0; j < 4; ++j)
        acc[i][j] = __builtin_amdgcn_mfma_f32_16x16x32_bf16(fal[i], fbh[j],
                                                            acc[i][j], 0, 0, 0);
  }

#pragma unroll
  for (int ti = 0; ti < 4; ++ti) {
#pragma unroll
    for (int r = 0; r < 4; ++r) {
      const int m = m0 + wm + ti * 16 + fq * 4 + r;
      if (m < N_NODES) {
#pragma unroll
        for (int tj = 0; tj < 4; ++tj) {
          const int n = n0 + wn + tj * 16 + fm;
          C[(size_t)m * FILTERS + n] = (_Float16)acc[ti][tj][r];
        }
      }
    }
  }
}

// ---------------------------------------------------------------------------
// Fused gather1 + relu + gemm2 (exact r2-verified kernel, 155 us / ~87% of
// the L1-miss-path line-rate roofline). One wave per node; one coalesced
// meta load per 64-edge chunk; per-edge (src,w) via readlane -> SGPR so
// the gather base is scalar; 8 independent half4 gathers in flight.
// ---------------------------------------------------------------------------
__global__ __launch_bounds__(256) void gather1_gemm2_kernel(
    const _Float16* __restrict__ xw1, const int* __restrict__ row_ptr,
    const int4* __restrict__ meta, const float* __restrict__ W2,
    _Float16* __restrict__ h2) {
  __shared__ float red[4][16][17];
  const int wave = threadIdx.x >> 6;
  const int lane = threadIdx.x & 63;
  const int node = blockIdx.x * 4 + wave;
  const int beg = row_ptr[node];
  const int end = row_ptr[node + 1];

  float acc[4] = {};
  const half4* __restrict__ xw1v = (const half4*)xw1;  // row stride = 64

  for (int c0 = beg; c0 < end; c0 += 64) {
    const int cnt = min(64, end - c0);
    const int4 mv = meta[c0 + ((lane < cnt) ? lane : 0)];

    for (int j = 0; j < cnt; j += 8) {
      int srcs[8];
      float ws[8];
#pragma unroll
      for (int u = 0; u < 8; ++u) {
        const int live = (j + u < cnt);
        const int l = live ? (j + u) : 0;
        srcs[u] = __builtin_amdgcn_readlane(mv.x, l);
        const int wb = __builtin_amdgcn_readlane(mv.y, l);
        ws[u] = live ? __int_as_float(wb) : 0.f;
      }
      half4 v[8];
#pragma unroll
      for (int u = 0; u < 8; ++u)
        v[u] = xw1v[(unsigned)srcs[u] * 64u + (unsigned)lane];
#pragma unroll
      for (int u = 0; u < 8; ++u)
#pragma unroll
        for (int i = 0; i < 4; ++i)
          acc[i] = fmaf(ws[u], (float)v[u][i], acc[i]);
    }
  }

  float r[4];
#pragma unroll
  for (int i = 0; i < 4; ++i) r[i] = fmaxf(acc[i], 0.f);

  // gemm2 partials: lane's k = lane*4 + j (covers all 256 k across 64 lanes)
  float p[16] = {};
#pragma unroll
  for (int j = 0; j < 4; ++j) {
    const float4* wr = (const float4*)(W2 + (size_t)(lane * 4 + j) * NUM_CLASSES);
#pragma unroll
    for (int c4 = 0; c4 < 4; ++c4) {
      const float4 wv = wr[c4];
      p[c4 * 4 + 0] = fmaf(r[j], wv.x, p[c4 * 4 + 0]);
      p[c4 * 4 + 1] = fmaf(r[j], wv.y, p[c4 * 4 + 1]);
      p[c4 * 4 + 2] = fmaf(r[j], wv.z, p[c4 * 4 + 2]);
      p[c4 * 4 + 3] = fmaf(r[j], wv.w, p[c4 * 4 + 3]);
    }
  }

#pragma unroll
  for (int off = 32; off >= 16; off >>= 1)
#pragma unroll
    for (int i = 0; i < 16; ++i) p[i] += __shfl_xor(p[i], off, 64);

  if (lane < 16) {
#pragma unroll
    for (int i = 0; i < 16; ++i) red[wave][lane][i] = p[i];
  }
  if (lane < 16) {
    float sum = 0.f;
#pragma unroll
    for (int i = 0; i < 16; ++i) sum += red[wave][i][lane];
    h2[(size_t)node * NUM_CLASSES + lane] = (_Float16)sum;
  }
}

// ---------------------------------------------------------------------------
// Gather2 + softmax via MFMA. One wave per 16-dst tile (50000 = 16*3125).
// 64-edge chunks: full-wave meta load, two independent 32-row gathers +
// two MFMAs per iteration, depth-1 meta prefetch.
// C layout: row = dst-local = (lane>>4)*4+reg, col = class = lane&15.
// ---------------------------------------------------------------------------
__global__ __launch_bounds__(256) void gather2_mfma_kernel(
    const _Float16* __restrict__ h2, const int* __restrict__ row_ptr,
    const int4* __restrict__ meta, float* __restrict__ out) {
  __shared__ _Float16 lds[4][16][72];  // per-wave slice
  const int wave = threadIdx.x >> 6;
  const int lane = threadIdx.x & 63;
  const int tile = blockIdx.x * 4 + wave;
  if (tile >= N_NODES / 16) return;
  const int t0 = tile * 16;
  const int beg = row_ptr[t0];
  const int end = row_ptr[t0 + 16];

  const int cls = lane & 15;   // class (N) / dst-local for A (M)
  const int kq = lane >> 4;    // k-octet
  const int erow = lane >> 1;  // staged edge 0..31
  const int part = lane & 1;   // class half for staging

  f32x4 acc = {0.f, 0.f, 0.f, 0.f};
  _Float16* myl = &lds[wave][0][0];

  if (beg < end) {
    const int last = end - 1;
    int e = beg + lane;
    int4 m = meta[(e <= last) ? e : last];
    float wv = (e <= last) ? __int_as_float(m.y) : 0.f;

    for (int c0 = beg; c0 < end; c0 += 64) {
      // depth-1 prefetch of next chunk's meta
      int4 mn = m;
      float wn = 0.f;
      const int c1 = c0 + 64;
      if (c1 < end) {
        const int en = c1 + lane;
        mn = meta[(en <= last) ? en : last];
        wn = (en <= last) ? __int_as_float(mn.y) : 0.f;
      }

      // stage 64 rows (two b128 gathers per lane, independent)
      const int se0 = __shfl(m.x, erow, 64);
      const int se1 = __shfl(m.x, 32 + erow, 64);
      const f16x8 r0 =
          *(const f16x8*)(h2 + (size_t)se0 * NUM_CLASSES + part * 8);
      const f16x8 r1 =
          *(const f16x8*)(h2 + (size_t)se1 * NUM_CLASSES + part * 8);

      // A-frags: Sel[m=dst-local][k=edge] = w_e * (dst_e == m)
      f16x8 a0, a1;
#pragma unroll
      for (int j = 0; j < 8; ++j) {
        const int ei = kq * 8 + j;
        const int d0 = __shfl(m.z, ei, 64) - t0;
        const float w0 = __shfl(wv, ei, 64);
        a0[j] = (d0 == cls) ? (_Float16)w0 : (_Float16)0.f;
        const int d1 = __shfl(m.z, 32 + ei, 64) - t0;
        const float w1 = __shfl(wv, 32 + ei, 64);
        a1[j] = (d1 == cls) ? (_Float16)w1 : (_Float16)0.f;
      }

      // transpose into wave-private LDS: [class][edge]
#pragma unroll
      for (int j = 0; j < 8; ++j) myl[(part * 8 + j) * 72 + erow] = r0[j];
#pragma unroll
      for (int j = 0; j < 8; ++j) myl[(part * 8 + j) * 72 + 32 + erow] = r1[j];

      // B-frags: B[k=edge][n=class] (contiguous b128 reads)
      const f16x8 b0 = *(const f16x8*)(myl + cls * 72 + kq * 8);
      const f16x8 b1 = *(const f16x8*)(myl + cls * 72 + 32 + kq * 8);

      acc = __builtin_amdgcn_mfma_f32_16x16x32_f16(a0, b0, acc, 0, 0, 0);
      acc = __builtin_amdgcn_mfma_f32_16x16x32_f16(a1, b1, acc, 0, 0, 0);

      m = mn;
      wv = wn;
    }
  }

  // softmax per dst (classes live across the quad's 16 lanes)
#pragma unroll
  for (int r = 0; r < 4; ++r) {
    const float a = acc[r];
    float mx = a;
#pragma unroll
    for (int off = 8; off >= 1; off >>= 1)
      mx = fmaxf(mx, __shfl_xor(mx, off, 16));
    const float ex = __expf(a - mx);
    float sm = ex;
#pragma unroll
    for (int off = 8; off >= 1; off >>= 1) sm += __shfl_xor(sm, off, 16);
    out[(size_t)(t0 + kq * 4 + r) * NUM_CLASSES + cls] = ex / sm;
  }
}

extern "C" void kernel_launch(void* const* d_in, const int* in_sizes, int n_in,
                              void* d_out, int out_size, void* d_ws,
                              size_t ws_size, hipStream_t stream) {
  const float* x = (const float*)d_in[0];
  const float* W1 = (const float*)d_in[1];
  const float* W2 = (const float*)d_in[2];
  const float* ew = (const float*)d_in[3];
  const int* esrc = (const int*)d_in[4];
  const int* edst = (const int*)d_in[5];
  float* out = (float*)d_out;

  _Float16* xw1 = (_Float16*)d_ws;                               // 25.6 MB
  _Float16* h2 = xw1 + (size_t)N_NODES * FILTERS;                // 1.6 MB
  int* row_ptr = (int*)(h2 + (size_t)N_NODES * NUM_CLASSES);     // 50001
  int* cursor = row_ptr + (N_NODES + 1);
  int* deg = cursor + N_NODES;
  int4* meta = (int4*)(((uintptr_t)(deg + N_NODES) + 15) & ~(uintptr_t)15);
  __bf16* w1th = (__bf16*)(meta + N_EDGES);                      // 25.6 MB meta
  __bf16* w1tl = w1th + D_FEAT * FILTERS;
  int* bsum = (int*)(w1tl + D_FEAT * FILTERS);                   // 256 ints

  // One cooperative launch: zero+split+hist+scan+fill
  void* args[] = {(void*)&W1,   (void*)&w1th, (void*)&w1tl, (void*)&esrc,
                  (void*)&edst, (void*)&ew,   (void*)&deg,  (void*)&row_ptr,
                  (void*)&cursor, (void*)&bsum, (void*)&meta};
  hipLaunchCooperativeKernel((const void*)csr_coop_kernel, dim3(CSR_NB),
                             dim3(256), args, 0, stream);

  dim3 g1((N_NODES + 127) / 128, FILTERS / 128);
  gemm1_mfma_kernel<<<g1, 256, 0, stream>>>(x, w1th, w1tl, xw1);

  gather1_gemm2_kernel<<<N_NODES / 4, 256, 0, stream>>>(xw1, row_ptr, meta, W2,
                                                        h2);

  gather2_mfma_kernel<<<(N_NODES / 16 + 3) / 4, 256, 0, stream>>>(h2, row_ptr,
                                                                  meta, out);
}

// Round 9
// 555.761 us; speedup vs baseline: 1.9067x; 1.9067x over previous
//
#include <hip/hip_runtime.h>

#define N_NODES 50000
#define N_EDGES 1600000
#define D_FEAT 512
#define FILTERS 256
#define NUM_CLASSES 16
#define NXCD 8

typedef __bf16 bf16x8 __attribute__((ext_vector_type(8)));
typedef float f32x4 __attribute__((ext_vector_type(4)));
typedef _Float16 half4 __attribute__((ext_vector_type(4)));
typedef _Float16 f16x8 __attribute__((ext_vector_type(8)));

#define GLOAD_LDS16(g, l)                                                  \
  __builtin_amdgcn_global_load_lds(                                        \
      (const __attribute__((address_space(1))) unsigned int*)(g),          \
      (__attribute__((address_space(3))) unsigned int*)(l), 16, 0, 0)

// ---------------------------------------------------------------------------
// Split W1 [512,256] fp32 -> W1^T hi/lo bf16 [256,512]
// ---------------------------------------------------------------------------
__global__ __launch_bounds__(256) void split_w1_kernel(
    const float* __restrict__ W1, __bf16* __restrict__ Wth,
    __bf16* __restrict__ Wtl) {
  const int idx = blockIdx.x * 256 + threadIdx.x;
  const int k = idx >> 8;
  const int n = idx & 255;
  const float v = W1[idx];
  const __bf16 h = (__bf16)v;
  const __bf16 l = (__bf16)(v - (float)h);
  Wth[n * D_FEAT + k] = h;
  Wtl[n * D_FEAT + k] = l;
}

// ---------------------------------------------------------------------------
// CSR build with XCD-LOCAL atomics (r9). 8 sub-histograms deg8[x][d],
// x = blockIdx.x & 7 == home XCD under round-robin dispatch, so the
// atomic'd lines stay in one XCD's L2 (r7/r8 showed cross-XCD atomic
// ping-pong = ~160MB write churn = ~250us). Fill uses per-XCD cursors
// over disjoint segments [row_ptr[d] + prefix_x(deg8[.][d])), so its
// atomics are local too and meta writes are plain stores.
// Mapping assumption affects speed only: correctness needs hist and fill
// to use the same x per block, which holds by construction.
// ---------------------------------------------------------------------------
__global__ __launch_bounds__(256) void hist8_kernel(
    const int* __restrict__ edst, int* __restrict__ deg8) {
  const int e = blockIdx.x * 256 + threadIdx.x;
  if (e >= N_EDGES) return;
  const int x = blockIdx.x & (NXCD - 1);
  atomicAdd(&deg8[x * N_NODES + edst[e]], 1);
}

#define SCAN_NB 196
__global__ __launch_bounds__(256) void scan_blocks_kernel(
    const int* __restrict__ deg8, int* __restrict__ row_ptr,
    int* __restrict__ bsum) {
  __shared__ int s[256];
  const int i = blockIdx.x * 256 + threadIdx.x;
  int v = 0;
  if (i < N_NODES) {
#pragma unroll
    for (int x = 0; x < NXCD; ++x) v += deg8[x * N_NODES + i];
  }
  s[threadIdx.x] = v;
  __syncthreads();
  for (int off = 1; off < 256; off <<= 1) {
    const int t = (threadIdx.x >= off) ? s[threadIdx.x - off] : 0;
    __syncthreads();
    s[threadIdx.x] += t;
    __syncthreads();
  }
  if (i < N_NODES) row_ptr[i] = s[threadIdx.x] - v;
  if (threadIdx.x == 255) bsum[blockIdx.x] = s[255];
}

__global__ __launch_bounds__(256) void scan_sums_kernel(int* __restrict__ bsum) {
  __shared__ int s[256];
  const int v = (threadIdx.x < SCAN_NB) ? bsum[threadIdx.x] : 0;
  s[threadIdx.x] = v;
  __syncthreads();
  for (int off = 1; off < 256; off <<= 1) {
    const int t = (threadIdx.x >= off) ? s[threadIdx.x - off] : 0;
    __syncthreads();
    s[threadIdx.x] += t;
    __syncthreads();
  }
  if (threadIdx.x < SCAN_NB) bsum[threadIdx.x] = s[threadIdx.x] - v;
}

// Finalize row_ptr and seed the 8 per-XCD cursors with disjoint segments.
__global__ __launch_bounds__(256) void scan_add_cursor8_kernel(
    int* __restrict__ row_ptr, const int* __restrict__ bsum,
    const int* __restrict__ deg8, int* __restrict__ cursor8) {
  const int i = blockIdx.x * 256 + threadIdx.x;
  if (i < N_NODES) {
    int run = row_ptr[i] + bsum[blockIdx.x];
    row_ptr[i] = run;
#pragma unroll
    for (int x = 0; x < NXCD; ++x) {
      cursor8[x * N_NODES + i] = run;
      run += deg8[x * N_NODES + i];
    }
  }
  if (i == 0) row_ptr[N_NODES] = N_EDGES;
}

// Fill: dst-sorted meta = (src, w_bits, dst, 0); XCD-local cursor atomics.
__global__ __launch_bounds__(256) void fill8_kernel(
    const int* __restrict__ esrc, const int* __restrict__ edst,
    const float* __restrict__ ew, int* __restrict__ cursor8,
    int4* __restrict__ meta) {
  const int e = blockIdx.x * 256 + threadIdx.x;
  if (e >= N_EDGES) return;
  const int x = blockIdx.x & (NXCD - 1);
  const int d = edst[e];
  const int pos = atomicAdd(&cursor8[x * N_NODES + d], 1);
  meta[pos] = make_int4(esrc[e], __float_as_int(ew[e]), d, 0);
}

// ---------------------------------------------------------------------------
// GEMM1 via MFMA bf16x3: XW1 = X @ W1, fp32-accurate, output stored fp16.
// ---------------------------------------------------------------------------
__global__ __launch_bounds__(256) void gemm1_mfma_kernel(
    const float* __restrict__ A, const __bf16* __restrict__ Bh,
    const __bf16* __restrict__ Bl, _Float16* __restrict__ C) {
  const int K = D_FEAT;
  __shared__ __bf16 sAh[128 * 32];
  __shared__ __bf16 sAl[128 * 32];
  __shared__ __bf16 sBh[128 * 32];
  __shared__ __bf16 sBl[128 * 32];

  const int tid = threadIdx.x;
  const int wave = tid >> 6;
  const int lane = tid & 63;
  const int wm = (wave >> 1) * 64;
  const int wn = (wave & 1) * 64;
  const int m0 = blockIdx.x * 128;
  const int n0 = blockIdx.y * 128;

  const int arow = tid >> 1;
  const int aks = (tid & 1) * 16;
  int am = m0 + arow;
  if (am >= N_NODES) am = N_NODES - 1;
  const float* aptr = A + (size_t)am * K + aks;

  const int lr = lane >> 2;
  const int lc = (lane & 3) * 8;
  const int fm = lane & 15;
  const int fq = lane >> 4;

  f32x4 acc[4][4] = {};

  for (int k0 = 0; k0 < K; k0 += 32) {
    const float4* ap = (const float4*)(aptr + k0);
    const float4 a0 = ap[0], a1 = ap[1], a2 = ap[2], a3 = ap[3];

    __syncthreads();

#pragma unroll
    for (int i = 0; i < 2; ++i) {
      const int row = wave * 32 + i * 16;
      GLOAD_LDS16(Bh + (size_t)(n0 + row + lr) * K + k0 + lc, sBh + row * 32);
      GLOAD_LDS16(Bl + (size_t)(n0 + row + lr) * K + k0 + lc, sBl + row * 32);
    }

    float va[16] = {a0.x, a0.y, a0.z, a0.w, a1.x, a1.y, a1.z, a1.w,
                    a2.x, a2.y, a2.z, a2.w, a3.x, a3.y, a3.z, a3.w};
    __bf16 hh[16], ll[16];
#pragma unroll
    for (int i = 0; i < 16; ++i) {
      const __bf16 h = (__bf16)va[i];
      hh[i] = h;
      ll[i] = (__bf16)(va[i] - (float)h);
    }
    *(bf16x8*)(sAh + arow * 32 + aks) = *(bf16x8*)&hh[0];
    *(bf16x8*)(sAh + arow * 32 + aks + 8) = *(bf16x8*)&hh[8];
    *(bf16x8*)(sAl + arow * 32 + aks) = *(bf16x8*)&ll[0];
    *(bf16x8*)(sAl + arow * 32 + aks + 8) = *(bf16x8*)&ll[8];

    __syncthreads();

    bf16x8 fah[4], fal[4], fbh[4], fbl[4];
#pragma unroll
    for (int t = 0; t < 4; ++t) {
      const int moff = (wm + t * 16 + fm) * 32 + fq * 8;
      fah[t] = *(const bf16x8*)(sAh + moff);
      fal[t] = *(const bf16x8*)(sAl + moff);
      const int noff = (wn + t * 16 + fm) * 32 + fq * 8;
      fbh[t] = *(const bf16x8*)(sBh + noff);
      fbl[t] = *(const bf16x8*)(sBl + noff);
    }
#pragma unroll
    for (int i = 0; i < 4; ++i)
#pragma unroll
      for (int j = 0; j < 4; ++j)
        acc[i][j] = __builtin_amdgcn_mfma_f32_16x16x32_bf16(fah[i], fbh[j],
                                                            acc[i][j], 0, 0, 0);
#pragma unroll
    for (int i = 0; i < 4; ++i)
#pragma unroll
      for (int j = 0; j < 4; ++j)
        acc[i][j] = __builtin_amdgcn_mfma_f32_16x16x32_bf16(fah[i], fbl[j],
                                                            acc[i][j], 0, 0, 0);
#pragma unroll
    for (int i = 0; i < 4; ++i)
#pragma unroll
      for (int j = 0; j < 4; ++j)
        acc[i][j] = __builtin_amdgcn_mfma_f32_16x16x32_bf16(fal[i], fbh[j],
                                                            acc[i][j], 0, 0, 0);
  }

#pragma unroll
  for (int ti = 0; ti < 4; ++ti) {
#pragma unroll
    for (int r = 0; r < 4; ++r) {
      const int m = m0 + wm + ti * 16 + fq * 4 + r;
      if (m < N_NODES) {
#pragma unroll
        for (int tj = 0; tj < 4; ++tj) {
          const int n = n0 + wn + tj * 16 + fm;
          C[(size_t)m * FILTERS + n] = (_Float16)acc[ti][tj][r];
        }
      }
    }
  }
}

// ---------------------------------------------------------------------------
// Fused gather1 + relu + gemm2 (exact r2-verified kernel, 155 us / ~87% of
// the L1-miss-path line-rate roofline). One wave per node; one coalesced
// meta load per 64-edge chunk; per-edge (src,w) via readlane -> SGPR so
// the gather base is scalar; 8 independent half4 gathers in flight.
// ---------------------------------------------------------------------------
__global__ __launch_bounds__(256) void gather1_gemm2_kernel(
    const _Float16* __restrict__ xw1, const int* __restrict__ row_ptr,
    const int4* __restrict__ meta, const float* __restrict__ W2,
    _Float16* __restrict__ h2) {
  __shared__ float red[4][16][17];
  const int wave = threadIdx.x >> 6;
  const int lane = threadIdx.x & 63;
  const int node = blockIdx.x * 4 + wave;
  const int beg = row_ptr[node];
  const int end = row_ptr[node + 1];

  float acc[4] = {};
  const half4* __restrict__ xw1v = (const half4*)xw1;  // row stride = 64

  for (int c0 = beg; c0 < end; c0 += 64) {
    const int cnt = min(64, end - c0);
    const int4 mv = meta[c0 + ((lane < cnt) ? lane : 0)];

    for (int j = 0; j < cnt; j += 8) {
      int srcs[8];
      float ws[8];
#pragma unroll
      for (int u = 0; u < 8; ++u) {
        const int live = (j + u < cnt);
        const int l = live ? (j + u) : 0;
        srcs[u] = __builtin_amdgcn_readlane(mv.x, l);
        const int wb = __builtin_amdgcn_readlane(mv.y, l);
        ws[u] = live ? __int_as_float(wb) : 0.f;
      }
      half4 v[8];
#pragma unroll
      for (int u = 0; u < 8; ++u)
        v[u] = xw1v[(unsigned)srcs[u] * 64u + (unsigned)lane];
#pragma unroll
      for (int u = 0; u < 8; ++u)
#pragma unroll
        for (int i = 0; i < 4; ++i)
          acc[i] = fmaf(ws[u], (float)v[u][i], acc[i]);
    }
  }

  float r[4];
#pragma unroll
  for (int i = 0; i < 4; ++i) r[i] = fmaxf(acc[i], 0.f);

  // gemm2 partials: lane's k = lane*4 + j (covers all 256 k across 64 lanes)
  float p[16] = {};
#pragma unroll
  for (int j = 0; j < 4; ++j) {
    const float4* wr = (const float4*)(W2 + (size_t)(lane * 4 + j) * NUM_CLASSES);
#pragma unroll
    for (int c4 = 0; c4 < 4; ++c4) {
      const float4 wv = wr[c4];
      p[c4 * 4 + 0] = fmaf(r[j], wv.x, p[c4 * 4 + 0]);
      p[c4 * 4 + 1] = fmaf(r[j], wv.y, p[c4 * 4 + 1]);
      p[c4 * 4 + 2] = fmaf(r[j], wv.z, p[c4 * 4 + 2]);
      p[c4 * 4 + 3] = fmaf(r[j], wv.w, p[c4 * 4 + 3]);
    }
  }

#pragma unroll
  for (int off = 32; off >= 16; off >>= 1)
#pragma unroll
    for (int i = 0; i < 16; ++i) p[i] += __shfl_xor(p[i], off, 64);

  if (lane < 16) {
#pragma unroll
    for (int i = 0; i < 16; ++i) red[wave][lane][i] = p[i];
  }
  if (lane < 16) {
    float sum = 0.f;
#pragma unroll
    for (int i = 0; i < 16; ++i) sum += red[wave][i][lane];
    h2[(size_t)node * NUM_CLASSES + lane] = (_Float16)sum;
  }
}

// ---------------------------------------------------------------------------
// Gather2 + softmax via MFMA. One wave per 16-dst tile (50000 = 16*3125).
// 64-edge chunks: full-wave meta load, two independent 32-row gathers +
// two MFMAs per iteration, depth-1 meta prefetch.
// C layout: row = dst-local = (lane>>4)*4+reg, col = class = lane&15.
// ---------------------------------------------------------------------------
__global__ __launch_bounds__(256) void gather2_mfma_kernel(
    const _Float16* __restrict__ h2, const int* __restrict__ row_ptr,
    const int4* __restrict__ meta, float* __restrict__ out) {
  __shared__ _Float16 lds[4][16][72];  // per-wave slice
  const int wave = threadIdx.x >> 6;
  const int lane = threadIdx.x & 63;
  const int tile = blockIdx.x * 4 + wave;
  if (tile >= N_NODES / 16) return;
  const int t0 = tile * 16;
  const int beg = row_ptr[t0];
  const int end = row_ptr[t0 + 16];

  const int cls = lane & 15;   // class (N) / dst-local for A (M)
  const int kq = lane >> 4;    // k-octet
  const int erow = lane >> 1;  // staged edge 0..31
  const int part = lane & 1;   // class half for staging

  f32x4 acc = {0.f, 0.f, 0.f, 0.f};
  _Float16* myl = &lds[wave][0][0];

  if (beg < end) {
    const int last = end - 1;
    int e = beg + lane;
    int4 m = meta[(e <= last) ? e : last];
    float wv = (e <= last) ? __int_as_float(m.y) : 0.f;

    for (int c0 = beg; c0 < end; c0 += 64) {
      // depth-1 prefetch of next chunk's meta
      int4 mn = m;
      float wn = 0.f;
      const int c1 = c0 + 64;
      if (c1 < end) {
        const int en = c1 + lane;
        mn = meta[(en <= last) ? en : last];
        wn = (en <= last) ? __int_as_float(mn.y) : 0.f;
      }

      // stage 64 rows (two b128 gathers per lane, independent)
      const int se0 = __shfl(m.x, erow, 64);
      const int se1 = __shfl(m.x, 32 + erow, 64);
      const f16x8 r0 =
          *(const f16x8*)(h2 + (size_t)se0 * NUM_CLASSES + part * 8);
      const f16x8 r1 =
          *(const f16x8*)(h2 + (size_t)se1 * NUM_CLASSES + part * 8);

      // A-frags: Sel[m=dst-local][k=edge] = w_e * (dst_e == m)
      f16x8 a0, a1;
#pragma unroll
      for (int j = 0; j < 8; ++j) {
        const int ei = kq * 8 + j;
        const int d0 = __shfl(m.z, ei, 64) - t0;
        const float w0 = __shfl(wv, ei, 64);
        a0[j] = (d0 == cls) ? (_Float16)w0 : (_Float16)0.f;
        const int d1 = __shfl(m.z, 32 + ei, 64) - t0;
        const float w1 = __shfl(wv, 32 + ei, 64);
        a1[j] = (d1 == cls) ? (_Float16)w1 : (_Float16)0.f;
      }

      // transpose into wave-private LDS: [class][edge]
#pragma unroll
      for (int j = 0; j < 8; ++j) myl[(part * 8 + j) * 72 + erow] = r0[j];
#pragma unroll
      for (int j = 0; j < 8; ++j) myl[(part * 8 + j) * 72 + 32 + erow] = r1[j];

      // B-frags: B[k=edge][n=class] (contiguous b128 reads)
      const f16x8 b0 = *(const f16x8*)(myl + cls * 72 + kq * 8);
      const f16x8 b1 = *(const f16x8*)(myl + cls * 72 + 32 + kq * 8);

      acc = __builtin_amdgcn_mfma_f32_16x16x32_f16(a0, b0, acc, 0, 0, 0);
      acc = __builtin_amdgcn_mfma_f32_16x16x32_f16(a1, b1, acc, 0, 0, 0);

      m = mn;
      wv = wn;
    }
  }

  // softmax per dst (classes live across the quad's 16 lanes)
#pragma unroll
  for (int r = 0; r < 4; ++r) {
    const float a = acc[r];
    float mx = a;
#pragma unroll
    for (int off = 8; off >= 1; off >>= 1)
      mx = fmaxf(mx, __shfl_xor(mx, off, 16));
    const float ex = __expf(a - mx);
    float sm = ex;
#pragma unroll
    for (int off = 8; off >= 1; off >>= 1) sm += __shfl_xor(sm, off, 16);
    out[(size_t)(t0 + kq * 4 + r) * NUM_CLASSES + cls] = ex / sm;
  }
}

extern "C" void kernel_launch(void* const* d_in, const int* in_sizes, int n_in,
                              void* d_out, int out_size, void* d_ws,
                              size_t ws_size, hipStream_t stream) {
  const float* x = (const float*)d_in[0];
  const float* W1 = (const float*)d_in[1];
  const float* W2 = (const float*)d_in[2];
  const float* ew = (const float*)d_in[3];
  const int* esrc = (const int*)d_in[4];
  const int* edst = (const int*)d_in[5];
  float* out = (float*)d_out;

  _Float16* xw1 = (_Float16*)d_ws;                               // 25.6 MB
  _Float16* h2 = xw1 + (size_t)N_NODES * FILTERS;                // 1.6 MB
  int* row_ptr = (int*)(h2 + (size_t)N_NODES * NUM_CLASSES);     // 50001
  int* deg8 = row_ptr + (N_NODES + 1);                           // 8*50000
  int* cursor8 = deg8 + NXCD * N_NODES;                          // 8*50000
  int4* meta = (int4*)(((uintptr_t)(cursor8 + NXCD * N_NODES) + 15) &
                       ~(uintptr_t)15);                          // 25.6 MB
  __bf16* w1th = (__bf16*)(meta + N_EDGES);
  __bf16* w1tl = w1th + D_FEAT * FILTERS;
  int* bsum = (int*)(w1tl + D_FEAT * FILTERS);                   // 256 ints

  hipMemsetAsync(deg8, 0, NXCD * N_NODES * sizeof(int), stream);
  hist8_kernel<<<(N_EDGES + 255) / 256, 256, 0, stream>>>(edst, deg8);
  scan_blocks_kernel<<<SCAN_NB, 256, 0, stream>>>(deg8, row_ptr, bsum);
  scan_sums_kernel<<<1, 256, 0, stream>>>(bsum);
  scan_add_cursor8_kernel<<<SCAN_NB, 256, 0, stream>>>(row_ptr, bsum, deg8,
                                                       cursor8);
  fill8_kernel<<<(N_EDGES + 255) / 256, 256, 0, stream>>>(esrc, edst, ew,
                                                          cursor8, meta);

  split_w1_kernel<<<(D_FEAT * FILTERS) / 256, 256, 0, stream>>>(W1, w1th, w1tl);
  dim3 g1((N_NODES + 127) / 128, FILTERS / 128);
  gemm1_mfma_kernel<<<g1, 256, 0, stream>>>(x, w1th, w1tl, xw1);

  gather1_gemm2_kernel<<<N_NODES / 4, 256, 0, stream>>>(xw1, row_ptr, meta, W2,
                                                        h2);

  gather2_mfma_kernel<<<(N_NODES / 16 + 3) / 4, 256, 0, stream>>>(h2, row_ptr,
                                                                  meta, out);
}

// Round 10
// 544.564 us; speedup vs baseline: 1.9459x; 1.0206x over previous
//
#include <hip/hip_runtime.h>

#define N_NODES 50000
#define N_EDGES 1600000
#define D_FEAT 512
#define FILTERS 256
#define NUM_CLASSES 16
#define NXCD 8

typedef __bf16 bf16x8 __attribute__((ext_vector_type(8)));
typedef float f32x4 __attribute__((ext_vector_type(4)));
typedef _Float16 half4 __attribute__((ext_vector_type(4)));
typedef _Float16 f16x8 __attribute__((ext_vector_type(8)));

#define GLOAD_LDS16(g, l)                                                  \
  __builtin_amdgcn_global_load_lds(                                        \
      (const __attribute__((address_space(1))) unsigned int*)(g),          \
      (__attribute__((address_space(3))) unsigned int*)(l), 16, 0, 0)

// ---------------------------------------------------------------------------
// CSR build, XCD-local atomics (r9-verified). r10: meta packed to 8 B:
// {x = src | dst_local4 << 16, y = w_f32}. src < 65536, dst_local = d & 15
// (gather2 tiles are 16-dst aligned). Exact packing -> numerics unchanged.
// ---------------------------------------------------------------------------
__global__ __launch_bounds__(256) void hist8_kernel(
    const int* __restrict__ edst, int* __restrict__ deg8) {
  const int e = blockIdx.x * 256 + threadIdx.x;
  if (e >= N_EDGES) return;
  const int x = blockIdx.x & (NXCD - 1);
  atomicAdd(&deg8[x * N_NODES + edst[e]], 1);
}

// scan_blocks + fused W1 split (independent work, same 196-block grid).
#define SCAN_NB 196
__global__ __launch_bounds__(256) void scan_blocks_kernel(
    const int* __restrict__ deg8, int* __restrict__ row_ptr,
    int* __restrict__ bsum, const float* __restrict__ W1,
    __bf16* __restrict__ Wth, __bf16* __restrict__ Wtl) {
  // W1 split: [512,256] fp32 -> W1^T hi/lo bf16 [256,512], grid-stride
  const int gtid = blockIdx.x * 256 + threadIdx.x;
  for (int i = gtid; i < D_FEAT * FILTERS; i += SCAN_NB * 256) {
    const float v = W1[i];
    const int k = i >> 8;
    const int n = i & 255;
    const __bf16 h = (__bf16)v;
    Wth[n * D_FEAT + k] = h;
    Wtl[n * D_FEAT + k] = (__bf16)(v - (float)h);
  }

  __shared__ int s[256];
  const int i = gtid;
  int v = 0;
  if (i < N_NODES) {
#pragma unroll
    for (int x = 0; x < NXCD; ++x) v += deg8[x * N_NODES + i];
  }
  s[threadIdx.x] = v;
  __syncthreads();
  for (int off = 1; off < 256; off <<= 1) {
    const int t = (threadIdx.x >= off) ? s[threadIdx.x - off] : 0;
    __syncthreads();
    s[threadIdx.x] += t;
    __syncthreads();
  }
  if (i < N_NODES) row_ptr[i] = s[threadIdx.x] - v;
  if (threadIdx.x == 255) bsum[blockIdx.x] = s[255];
}

// Finalize row_ptr and seed 8 per-XCD cursors. Each block computes its own
// bsum exclusive prefix in-block (<=196 ints from L2) -- no scan_sums pass.
__global__ __launch_bounds__(256) void scan_add_cursor8_kernel(
    int* __restrict__ row_ptr, const int* __restrict__ bsum,
    const int* __restrict__ deg8, int* __restrict__ cursor8) {
  __shared__ int wsum[4];
  const int lane = threadIdx.x & 63;
  const int wave = threadIdx.x >> 6;
  int v = (threadIdx.x < blockIdx.x) ? bsum[threadIdx.x] : 0;  // bid<=195<256
#pragma unroll
  for (int off = 32; off >= 1; off >>= 1) v += __shfl_xor(v, off, 64);
  if (lane == 0) wsum[wave] = v;
  __syncthreads();
  const int boff = wsum[0] + wsum[1] + wsum[2] + wsum[3];

  const int i = blockIdx.x * 256 + threadIdx.x;
  if (i < N_NODES) {
    int run = row_ptr[i] + boff;
    row_ptr[i] = run;
#pragma unroll
    for (int x = 0; x < NXCD; ++x) {
      cursor8[x * N_NODES + i] = run;
      run += deg8[x * N_NODES + i];
    }
  }
  if (i == 0) row_ptr[N_NODES] = N_EDGES;
}

// Fill: dst-sorted packed meta; XCD-local cursor atomics; 8 B scatter.
__global__ __launch_bounds__(256) void fill8_kernel(
    const int* __restrict__ esrc, const int* __restrict__ edst,
    const float* __restrict__ ew, int* __restrict__ cursor8,
    uint2* __restrict__ meta8) {
  const int e = blockIdx.x * 256 + threadIdx.x;
  if (e >= N_EDGES) return;
  const int x = blockIdx.x & (NXCD - 1);
  const int d = edst[e];
  const int pos = atomicAdd(&cursor8[x * N_NODES + d], 1);
  meta8[pos] = make_uint2((unsigned)esrc[e] | ((unsigned)(d & 15) << 16),
                          __float_as_uint(ew[e]));
}

// ---------------------------------------------------------------------------
// GEMM1 via MFMA bf16x3: XW1 = X @ W1, fp32-accurate, output stored fp16.
// ---------------------------------------------------------------------------
__global__ __launch_bounds__(256) void gemm1_mfma_kernel(
    const float* __restrict__ A, const __bf16* __restrict__ Bh,
    const __bf16* __restrict__ Bl, _Float16* __restrict__ C) {
  const int K = D_FEAT;
  __shared__ __bf16 sAh[128 * 32];
  __shared__ __bf16 sAl[128 * 32];
  __shared__ __bf16 sBh[128 * 32];
  __shared__ __bf16 sBl[128 * 32];

  const int tid = threadIdx.x;
  const int wave = tid >> 6;
  const int lane = tid & 63;
  const int wm = (wave >> 1) * 64;
  const int wn = (wave & 1) * 64;
  const int m0 = blockIdx.x * 128;
  const int n0 = blockIdx.y * 128;

  const int arow = tid >> 1;
  const int aks = (tid & 1) * 16;
  int am = m0 + arow;
  if (am >= N_NODES) am = N_NODES - 1;
  const float* aptr = A + (size_t)am * K + aks;

  const int lr = lane >> 2;
  const int lc = (lane & 3) * 8;
  const int fm = lane & 15;
  const int fq = lane >> 4;

  f32x4 acc[4][4] = {};

  for (int k0 = 0; k0 < K; k0 += 32) {
    const float4* ap = (const float4*)(aptr + k0);
    const float4 a0 = ap[0], a1 = ap[1], a2 = ap[2], a3 = ap[3];

    __syncthreads();

#pragma unroll
    for (int i = 0; i < 2; ++i) {
      const int row = wave * 32 + i * 16;
      GLOAD_LDS16(Bh + (size_t)(n0 + row + lr) * K + k0 + lc, sBh + row * 32);
      GLOAD_LDS16(Bl + (size_t)(n0 + row + lr) * K + k0 + lc, sBl + row * 32);
    }

    float va[16] = {a0.x, a0.y, a0.z, a0.w, a1.x, a1.y, a1.z, a1.w,
                    a2.x, a2.y, a2.z, a2.w, a3.x, a3.y, a3.z, a3.w};
    __bf16 hh[16], ll[16];
#pragma unroll
    for (int i = 0; i < 16; ++i) {
      const __bf16 h = (__bf16)va[i];
      hh[i] = h;
      ll[i] = (__bf16)(va[i] - (float)h);
    }
    *(bf16x8*)(sAh + arow * 32 + aks) = *(bf16x8*)&hh[0];
    *(bf16x8*)(sAh + arow * 32 + aks + 8) = *(bf16x8*)&hh[8];
    *(bf16x8*)(sAl + arow * 32 + aks) = *(bf16x8*)&ll[0];
    *(bf16x8*)(sAl + arow * 32 + aks + 8) = *(bf16x8*)&ll[8];

    __syncthreads();

    bf16x8 fah[4], fal[4], fbh[4], fbl[4];
#pragma unroll
    for (int t = 0; t < 4; ++t) {
      const int moff = (wm + t * 16 + fm) * 32 + fq * 8;
      fah[t] = *(const bf16x8*)(sAh + moff);
      fal[t] = *(const bf16x8*)(sAl + moff);
      const int noff = (wn + t * 16 + fm) * 32 + fq * 8;
      fbh[t] = *(const bf16x8*)(sBh + noff);
      fbl[t] = *(const bf16x8*)(sBl + noff);
    }
#pragma unroll
    for (int i = 0; i < 4; ++i)
#pragma unroll
      for (int j = 0; j < 4; ++j)
        acc[i][j] = __builtin_amdgcn_mfma_f32_16x16x32_bf16(fah[i], fbh[j],
                                                            acc[i][j], 0, 0, 0);
#pragma unroll
    for (int i = 0; i < 4; ++i)
#pragma unroll
      for (int j = 0; j < 4; ++j)
        acc[i][j] = __builtin_amdgcn_mfma_f32_16x16x32_bf16(fah[i], fbl[j],
                                                            acc[i][j], 0, 0, 0);
#pragma unroll
    for (int i = 0; i < 4; ++i)
#pragma unroll
      for (int j = 0; j < 4; ++j)
        acc[i][j] = __builtin_amdgcn_mfma_f32_16x16x32_bf16(fal[i], fbh[j],
                                                            acc[i][j], 0, 0, 0);
  }

#pragma unroll
  for (int ti = 0; ti < 4; ++ti) {
#pragma unroll
    for (int r = 0; r < 4; ++r) {
      const int m = m0 + wm + ti * 16 + fq * 4 + r;
      if (m < N_NODES) {
#pragma unroll
        for (int tj = 0; tj < 4; ++tj) {
          const int n = n0 + wn + tj * 16 + fm;
          C[(size_t)m * FILTERS + n] = (_Float16)acc[ti][tj][r];
        }
      }
    }
  }
}

// ---------------------------------------------------------------------------
// Fused gather1 + relu + gemm2 (r2-verified structure, 155 us). One wave
// per node; one coalesced 8B meta load per 64-edge chunk; per-edge (src,w)
// via readlane -> SGPR (scalar gather base); 8 half4 gathers in flight.
// ---------------------------------------------------------------------------
__global__ __launch_bounds__(256) void gather1_gemm2_kernel(
    const _Float16* __restrict__ xw1, const int* __restrict__ row_ptr,
    const uint2* __restrict__ meta8, const float* __restrict__ W2,
    _Float16* __restrict__ h2) {
  __shared__ float red[4][16][17];
  const int wave = threadIdx.x >> 6;
  const int lane = threadIdx.x & 63;
  const int node = blockIdx.x * 4 + wave;
  const int beg = row_ptr[node];
  const int end = row_ptr[node + 1];

  float acc[4] = {};
  const half4* __restrict__ xw1v = (const half4*)xw1;  // row stride = 64

  for (int c0 = beg; c0 < end; c0 += 64) {
    const int cnt = min(64, end - c0);
    const uint2 mv = meta8[c0 + ((lane < cnt) ? lane : 0)];

    for (int j = 0; j < cnt; j += 8) {
      int srcs[8];
      float ws[8];
#pragma unroll
      for (int u = 0; u < 8; ++u) {
        const int live = (j + u < cnt);
        const int l = live ? (j + u) : 0;
        srcs[u] = __builtin_amdgcn_readlane((int)mv.x, l) & 0xFFFF;
        const int wb = __builtin_amdgcn_readlane((int)mv.y, l);
        ws[u] = live ? __int_as_float(wb) : 0.f;
      }
      half4 v[8];
#pragma unroll
      for (int u = 0; u < 8; ++u)
        v[u] = xw1v[(unsigned)srcs[u] * 64u + (unsigned)lane];
#pragma unroll
      for (int u = 0; u < 8; ++u)
#pragma unroll
        for (int i = 0; i < 4; ++i)
          acc[i] = fmaf(ws[u], (float)v[u][i], acc[i]);
    }
  }

  float r[4];
#pragma unroll
  for (int i = 0; i < 4; ++i) r[i] = fmaxf(acc[i], 0.f);

  // gemm2 partials: lane's k = lane*4 + j (covers all 256 k across 64 lanes)
  float p[16] = {};
#pragma unroll
  for (int j = 0; j < 4; ++j) {
    const float4* wr = (const float4*)(W2 + (size_t)(lane * 4 + j) * NUM_CLASSES);
#pragma unroll
    for (int c4 = 0; c4 < 4; ++c4) {
      const float4 wv = wr[c4];
      p[c4 * 4 + 0] = fmaf(r[j], wv.x, p[c4 * 4 + 0]);
      p[c4 * 4 + 1] = fmaf(r[j], wv.y, p[c4 * 4 + 1]);
      p[c4 * 4 + 2] = fmaf(r[j], wv.z, p[c4 * 4 + 2]);
      p[c4 * 4 + 3] = fmaf(r[j], wv.w, p[c4 * 4 + 3]);
    }
  }

#pragma unroll
  for (int off = 32; off >= 16; off >>= 1)
#pragma unroll
    for (int i = 0; i < 16; ++i) p[i] += __shfl_xor(p[i], off, 64);

  if (lane < 16) {
#pragma unroll
    for (int i = 0; i < 16; ++i) red[wave][lane][i] = p[i];
  }
  if (lane < 16) {
    float sum = 0.f;
#pragma unroll
    for (int i = 0; i < 16; ++i) sum += red[wave][i][lane];
    h2[(size_t)node * NUM_CLASSES + lane] = (_Float16)sum;
  }
}

// ---------------------------------------------------------------------------
// Gather2 + softmax via MFMA. One wave per 16-dst tile. 64-edge chunks,
// depth-1 meta prefetch, two 32-row gathers + two MFMAs per iteration.
// dst-local comes from meta8 bits 16..19 (tile-aligned).
// ---------------------------------------------------------------------------
__global__ __launch_bounds__(256) void gather2_mfma_kernel(
    const _Float16* __restrict__ h2, const int* __restrict__ row_ptr,
    const uint2* __restrict__ meta8, float* __restrict__ out) {
  __shared__ _Float16 lds[4][16][72];  // per-wave slice
  const int wave = threadIdx.x >> 6;
  const int lane = threadIdx.x & 63;
  const int tile = blockIdx.x * 4 + wave;
  if (tile >= N_NODES / 16) return;
  const int t0 = tile * 16;
  const int beg = row_ptr[t0];
  const int end = row_ptr[t0 + 16];

  const int cls = lane & 15;   // class (N) / dst-local for A (M)
  const int kq = lane >> 4;    // k-octet
  const int erow = lane >> 1;  // staged edge 0..31
  const int part = lane & 1;   // class half for staging

  f32x4 acc = {0.f, 0.f, 0.f, 0.f};
  _Float16* myl = &lds[wave][0][0];

  if (beg < end) {
    const int last = end - 1;
    int e = beg + lane;
    uint2 m = meta8[(e <= last) ? e : last];
    float wv = (e <= last) ? __uint_as_float(m.y) : 0.f;

    for (int c0 = beg; c0 < end; c0 += 64) {
      // depth-1 prefetch of next chunk's meta
      uint2 mn = m;
      float wn = 0.f;
      const int c1 = c0 + 64;
      if (c1 < end) {
        const int en = c1 + lane;
        mn = meta8[(en <= last) ? en : last];
        wn = (en <= last) ? __uint_as_float(mn.y) : 0.f;
      }

      // stage 64 rows (two b128 gathers per lane, independent)
      const int se0 = __shfl((int)m.x, erow, 64) & 0xFFFF;
      const int se1 = __shfl((int)m.x, 32 + erow, 64) & 0xFFFF;
      const f16x8 r0 =
          *(const f16x8*)(h2 + (size_t)se0 * NUM_CLASSES + part * 8);
      const f16x8 r1 =
          *(const f16x8*)(h2 + (size_t)se1 * NUM_CLASSES + part * 8);

      // A-frags: Sel[m=dst-local][k=edge] = w_e * (dst_local_e == m)
      f16x8 a0, a1;
#pragma unroll
      for (int j = 0; j < 8; ++j) {
        const int ei = kq * 8 + j;
        const int p0 = __shfl((int)m.x, ei, 64);
        const float w0 = __shfl(wv, ei, 64);
        a0[j] = (((p0 >> 16) & 15) == cls) ? (_Float16)w0 : (_Float16)0.f;
        const int p1 = __shfl((int)m.x, 32 + ei, 64);
        const float w1 = __shfl(wv, 32 + ei, 64);
        a1[j] = (((p1 >> 16) & 15) == cls) ? (_Float16)w1 : (_Float16)0.f;
      }

      // transpose into wave-private LDS: [class][edge]
#pragma unroll
      for (int j = 0; j < 8; ++j) myl[(part * 8 + j) * 72 + erow] = r0[j];
#pragma unroll
      for (int j = 0; j < 8; ++j) myl[(part * 8 + j) * 72 + 32 + erow] = r1[j];

      // B-frags: B[k=edge][n=class] (contiguous b128 reads)
      const f16x8 b0 = *(const f16x8*)(myl + cls * 72 + kq * 8);
      const f16x8 b1 = *(const f16x8*)(myl + cls * 72 + 32 + kq * 8);

      acc = __builtin_amdgcn_mfma_f32_16x16x32_f16(a0, b0, acc, 0, 0, 0);
      acc = __builtin_amdgcn_mfma_f32_16x16x32_f16(a1, b1, acc, 0, 0, 0);

      m = mn;
      wv = wn;
    }
  }

  // softmax per dst (classes live across the quad's 16 lanes)
#pragma unroll
  for (int r = 0; r < 4; ++r) {
    const float a = acc[r];
    float mx = a;
#pragma unroll
    for (int off = 8; off >= 1; off >>= 1)
      mx = fmaxf(mx, __shfl_xor(mx, off, 16));
    const float ex = __expf(a - mx);
    float sm = ex;
#pragma unroll
    for (int off = 8; off >= 1; off >>= 1) sm += __shfl_xor(sm, off, 16);
    out[(size_t)(t0 + kq * 4 + r) * NUM_CLASSES + cls] = ex / sm;
  }
}

extern "C" void kernel_launch(void* const* d_in, const int* in_sizes, int n_in,
                              void* d_out, int out_size, void* d_ws,
                              size_t ws_size, hipStream_t stream) {
  const float* x = (const float*)d_in[0];
  const float* W1 = (const float*)d_in[1];
  const float* W2 = (const float*)d_in[2];
  const float* ew = (const float*)d_in[3];
  const int* esrc = (const int*)d_in[4];
  const int* edst = (const int*)d_in[5];
  float* out = (float*)d_out;

  _Float16* xw1 = (_Float16*)d_ws;                               // 25.6 MB
  _Float16* h2 = xw1 + (size_t)N_NODES * FILTERS;                // 1.6 MB
  int* row_ptr = (int*)(h2 + (size_t)N_NODES * NUM_CLASSES);     // 50001
  int* deg8 = row_ptr + (N_NODES + 1);                           // 8*50000
  int* cursor8 = deg8 + NXCD * N_NODES;                          // 8*50000
  uint2* meta8 = (uint2*)(((uintptr_t)(cursor8 + NXCD * N_NODES) + 15) &
                          ~(uintptr_t)15);                       // 12.8 MB
  __bf16* w1th = (__bf16*)(meta8 + N_EDGES);
  __bf16* w1tl = w1th + D_FEAT * FILTERS;
  int* bsum = (int*)(w1tl + D_FEAT * FILTERS);                   // 256 ints

  hipMemsetAsync(deg8, 0, NXCD * N_NODES * sizeof(int), stream);
  hist8_kernel<<<(N_EDGES + 255) / 256, 256, 0, stream>>>(edst, deg8);
  scan_blocks_kernel<<<SCAN_NB, 256, 0, stream>>>(deg8, row_ptr, bsum, W1,
                                                  w1th, w1tl);
  scan_add_cursor8_kernel<<<SCAN_NB, 256, 0, stream>>>(row_ptr, bsum, deg8,
                                                       cursor8);
  fill8_kernel<<<(N_EDGES + 255) / 256, 256, 0, stream>>>(esrc, edst, ew,
                                                          cursor8, meta8);

  dim3 g1((N_NODES + 127) / 128, FILTERS / 128);
  gemm1_mfma_kernel<<<g1, 256, 0, stream>>>(x, w1th, w1tl, xw1);

  gather1_gemm2_kernel<<<N_NODES / 4, 256, 0, stream>>>(xw1, row_ptr, meta8,
                                                        W2, h2);

  gather2_mfma_kernel<<<(N_NODES / 16 + 3) / 4, 256, 0, stream>>>(h2, row_ptr,
                                                                  meta8, out);
}

// Round 11
// 489.739 us; speedup vs baseline: 2.1638x; 1.1119x over previous
//
#include <hip/hip_runtime.h>

#define N_NODES 50000
#define N_EDGES 1600000
#define D_FEAT 512
#define FILTERS 256
#define NUM_CLASSES 16
#define NXCD 8

typedef __bf16 bf16x8 __attribute__((ext_vector_type(8)));
typedef float f32x4 __attribute__((ext_vector_type(4)));
typedef _Float16 half4 __attribute__((ext_vector_type(4)));
typedef _Float16 f16x8 __attribute__((ext_vector_type(8)));

#define GLOAD_LDS16(g, l)                                                  \
  __builtin_amdgcn_global_load_lds(                                        \
      (const __attribute__((address_space(1))) unsigned int*)(g),          \
      (__attribute__((address_space(3))) unsigned int*)(l), 16, 0, 0)

// ---------------------------------------------------------------------------
// CSR build, XCD-split atomics (r9/r10-verified). meta packed 8 B:
// {x = src | dst_local4 << 16, y = w_f32}. Sub-histogram index derived
// from the EDGE id (x = (e>>8)&7) so hist and the fused fill agree
// regardless of which block processes the edge.
// hist8 also carries the W1 split (independent work, frees a launch).
// ---------------------------------------------------------------------------
__global__ __launch_bounds__(256) void hist8_kernel(
    const int* __restrict__ edst, int* __restrict__ deg8,
    const float* __restrict__ W1, __bf16* __restrict__ Wth,
    __bf16* __restrict__ Wtl) {
  const int e = blockIdx.x * 256 + threadIdx.x;
  if (e < D_FEAT * FILTERS) {  // W1 split: [512,256] fp32 -> hi/lo bf16^T
    const float v = W1[e];
    const int k = e >> 8;
    const int n = e & 255;
    const __bf16 h = (__bf16)v;
    Wth[n * D_FEAT + k] = h;
    Wtl[n * D_FEAT + k] = (__bf16)(v - (float)h);
  }
  if (e >= N_EDGES) return;
  const int x = (e >> 8) & (NXCD - 1);
  atomicAdd(&deg8[x * N_NODES + edst[e]], 1);
}

#define SCAN_NB 196
__global__ __launch_bounds__(256) void scan_blocks_kernel(
    const int* __restrict__ deg8, int* __restrict__ row_ptr,
    int* __restrict__ bsum) {
  __shared__ int s[256];
  const int i = blockIdx.x * 256 + threadIdx.x;
  int v = 0;
  if (i < N_NODES) {
#pragma unroll
    for (int x = 0; x < NXCD; ++x) v += deg8[x * N_NODES + i];
  }
  s[threadIdx.x] = v;
  __syncthreads();
  for (int off = 1; off < 256; off <<= 1) {
    const int t = (threadIdx.x >= off) ? s[threadIdx.x - off] : 0;
    __syncthreads();
    s[threadIdx.x] += t;
    __syncthreads();
  }
  if (i < N_NODES) row_ptr[i] = s[threadIdx.x] - v;
  if (threadIdx.x == 255) bsum[blockIdx.x] = s[255];
}

// Finalize row_ptr and seed 8 per-slot cursors; in-block bsum prefix (r10).
__global__ __launch_bounds__(256) void scan_add_cursor8_kernel(
    int* __restrict__ row_ptr, const int* __restrict__ bsum,
    const int* __restrict__ deg8, int* __restrict__ cursor8) {
  __shared__ int wsum[4];
  const int lane = threadIdx.x & 63;
  const int wave = threadIdx.x >> 6;
  int v = (threadIdx.x < blockIdx.x) ? bsum[threadIdx.x] : 0;  // bid<=195<256
#pragma unroll
  for (int off = 32; off >= 1; off >>= 1) v += __shfl_xor(v, off, 64);
  if (lane == 0) wsum[wave] = v;
  __syncthreads();
  const int boff = wsum[0] + wsum[1] + wsum[2] + wsum[3];

  const int i = blockIdx.x * 256 + threadIdx.x;
  if (i < N_NODES) {
    int run = row_ptr[i] + boff;
    row_ptr[i] = run;
#pragma unroll
    for (int x = 0; x < NXCD; ++x) {
      cursor8[x * N_NODES + i] = run;
      run += deg8[x * N_NODES + i];
    }
  }
  if (i == 0) row_ptr[N_NODES] = N_EDGES;
}

// ---------------------------------------------------------------------------
// FAT kernel: gemm1 (blocks 0..781) CONCURRENT WITH fill (blocks 782..).
// gemm1 and fill have no data dependency (gemm1 needs only Wth/Wtl from
// hist8; fill needs only cursor8). Block-range fusion gives the overlap
// multi-stream would (events are forbidden in this harness). fill's
// ~30 MB of latency-bound traffic hides under gemm1's MFMA compute.
// ---------------------------------------------------------------------------
#define G1_BX 391  // ceil(50000/128)
#define G1_BLOCKS (G1_BX * 2)
__global__ __launch_bounds__(256) void gemm1_fill_kernel(
    const float* __restrict__ A, const __bf16* __restrict__ Bh,
    const __bf16* __restrict__ Bl, _Float16* __restrict__ C,
    const int* __restrict__ esrc, const int* __restrict__ edst,
    const float* __restrict__ ew, int* __restrict__ cursor8,
    uint2* __restrict__ meta8) {
  __shared__ __bf16 sAh[128 * 32];
  __shared__ __bf16 sAl[128 * 32];
  __shared__ __bf16 sBh[128 * 32];
  __shared__ __bf16 sBl[128 * 32];

  if (blockIdx.x >= G1_BLOCKS) {
    // ---- fill branch: dst-sorted packed meta, slot-split cursor atomics
    const int e = (blockIdx.x - G1_BLOCKS) * 256 + threadIdx.x;
    if (e < N_EDGES) {
      const int x = (e >> 8) & (NXCD - 1);
      const int d = edst[e];
      const int pos = atomicAdd(&cursor8[x * N_NODES + d], 1);
      meta8[pos] = make_uint2((unsigned)esrc[e] | ((unsigned)(d & 15) << 16),
                              __float_as_uint(ew[e]));
    }
    return;
  }

  // ---- gemm1 branch (r2-verified bf16x3 MFMA): XW1 = X @ W1 -> fp16
  const int K = D_FEAT;
  const int tid = threadIdx.x;
  const int wave = tid >> 6;
  const int lane = tid & 63;
  const int wm = (wave >> 1) * 64;
  const int wn = (wave & 1) * 64;
  const int m0 = (blockIdx.x % G1_BX) * 128;
  const int n0 = (blockIdx.x / G1_BX) * 128;

  const int arow = tid >> 1;
  const int aks = (tid & 1) * 16;
  int am = m0 + arow;
  if (am >= N_NODES) am = N_NODES - 1;
  const float* aptr = A + (size_t)am * K + aks;

  const int lr = lane >> 2;
  const int lc = (lane & 3) * 8;
  const int fm = lane & 15;
  const int fq = lane >> 4;

  f32x4 acc[4][4] = {};

  for (int k0 = 0; k0 < K; k0 += 32) {
    const float4* ap = (const float4*)(aptr + k0);
    const float4 a0 = ap[0], a1 = ap[1], a2 = ap[2], a3 = ap[3];

    __syncthreads();

#pragma unroll
    for (int i = 0; i < 2; ++i) {
      const int row = wave * 32 + i * 16;
      GLOAD_LDS16(Bh + (size_t)(n0 + row + lr) * K + k0 + lc, sBh + row * 32);
      GLOAD_LDS16(Bl + (size_t)(n0 + row + lr) * K + k0 + lc, sBl + row * 32);
    }

    float va[16] = {a0.x, a0.y, a0.z, a0.w, a1.x, a1.y, a1.z, a1.w,
                    a2.x, a2.y, a2.z, a2.w, a3.x, a3.y, a3.z, a3.w};
    __bf16 hh[16], ll[16];
#pragma unroll
    for (int i = 0; i < 16; ++i) {
      const __bf16 h = (__bf16)va[i];
      hh[i] = h;
      ll[i] = (__bf16)(va[i] - (float)h);
    }
    *(bf16x8*)(sAh + arow * 32 + aks) = *(bf16x8*)&hh[0];
    *(bf16x8*)(sAh + arow * 32 + aks + 8) = *(bf16x8*)&hh[8];
    *(bf16x8*)(sAl + arow * 32 + aks) = *(bf16x8*)&ll[0];
    *(bf16x8*)(sAl + arow * 32 + aks + 8) = *(bf16x8*)&ll[8];

    __syncthreads();

    bf16x8 fah[4], fal[4], fbh[4], fbl[4];
#pragma unroll
    for (int t = 0; t < 4; ++t) {
      const int moff = (wm + t * 16 + fm) * 32 + fq * 8;
      fah[t] = *(const bf16x8*)(sAh + moff);
      fal[t] = *(const bf16x8*)(sAl + moff);
      const int noff = (wn + t * 16 + fm) * 32 + fq * 8;
      fbh[t] = *(const bf16x8*)(sBh + noff);
      fbl[t] = *(const bf16x8*)(sBl + noff);
    }
#pragma unroll
    for (int i = 0; i < 4; ++i)
#pragma unroll
      for (int j = 0; j < 4; ++j)
        acc[i][j] = __builtin_amdgcn_mfma_f32_16x16x32_bf16(fah[i], fbh[j],
                                                            acc[i][j], 0, 0, 0);
#pragma unroll
    for (int i = 0; i < 4; ++i)
#pragma unroll
      for (int j = 0; j < 4; ++j)
        acc[i][j] = __builtin_amdgcn_mfma_f32_16x16x32_bf16(fah[i], fbl[j],
                                                            acc[i][j], 0, 0, 0);
#pragma unroll
    for (int i = 0; i < 4; ++i)
#pragma unroll
      for (int j = 0; j < 4; ++j)
        acc[i][j] = __builtin_amdgcn_mfma_f32_16x16x32_bf16(fal[i], fbh[j],
                                                            acc[i][j], 0, 0, 0);
  }

#pragma unroll
  for (int ti = 0; ti < 4; ++ti) {
#pragma unroll
    for (int r = 0; r < 4; ++r) {
      const int m = m0 + wm + ti * 16 + fq * 4 + r;
      if (m < N_NODES) {
#pragma unroll
        for (int tj = 0; tj < 4; ++tj) {
          const int n = n0 + wn + tj * 16 + fm;
          C[(size_t)m * FILTERS + n] = (_Float16)acc[ti][tj][r];
        }
      }
    }
  }
}

// ---------------------------------------------------------------------------
// Fused gather1 + relu + gemm2 (r2-verified structure, 155 us floor). One
// wave per node; one coalesced 8B meta load per 64-edge chunk; per-edge
// (src,w) via readlane -> SGPR (scalar gather base); 8 gathers in flight.
// ---------------------------------------------------------------------------
__global__ __launch_bounds__(256) void gather1_gemm2_kernel(
    const _Float16* __restrict__ xw1, const int* __restrict__ row_ptr,
    const uint2* __restrict__ meta8, const float* __restrict__ W2,
    _Float16* __restrict__ h2) {
  __shared__ float red[4][16][17];
  const int wave = threadIdx.x >> 6;
  const int lane = threadIdx.x & 63;
  const int node = blockIdx.x * 4 + wave;
  const int beg = row_ptr[node];
  const int end = row_ptr[node + 1];

  float acc[4] = {};
  const half4* __restrict__ xw1v = (const half4*)xw1;  // row stride = 64

  for (int c0 = beg; c0 < end; c0 += 64) {
    const int cnt = min(64, end - c0);
    const uint2 mv = meta8[c0 + ((lane < cnt) ? lane : 0)];

    for (int j = 0; j < cnt; j += 8) {
      int srcs[8];
      float ws[8];
#pragma unroll
      for (int u = 0; u < 8; ++u) {
        const int live = (j + u < cnt);
        const int l = live ? (j + u) : 0;
        srcs[u] = __builtin_amdgcn_readlane((int)mv.x, l) & 0xFFFF;
        const int wb = __builtin_amdgcn_readlane((int)mv.y, l);
        ws[u] = live ? __int_as_float(wb) : 0.f;
      }
      half4 v[8];
#pragma unroll
      for (int u = 0; u < 8; ++u)
        v[u] = xw1v[(unsigned)srcs[u] * 64u + (unsigned)lane];
#pragma unroll
      for (int u = 0; u < 8; ++u)
#pragma unroll
        for (int i = 0; i < 4; ++i)
          acc[i] = fmaf(ws[u], (float)v[u][i], acc[i]);
    }
  }

  float r[4];
#pragma unroll
  for (int i = 0; i < 4; ++i) r[i] = fmaxf(acc[i], 0.f);

  // gemm2 partials: lane's k = lane*4 + j (covers all 256 k across 64 lanes)
  float p[16] = {};
#pragma unroll
  for (int j = 0; j < 4; ++j) {
    const float4* wr = (const float4*)(W2 + (size_t)(lane * 4 + j) * NUM_CLASSES);
#pragma unroll
    for (int c4 = 0; c4 < 4; ++c4) {
      const float4 wv = wr[c4];
      p[c4 * 4 + 0] = fmaf(r[j], wv.x, p[c4 * 4 + 0]);
      p[c4 * 4 + 1] = fmaf(r[j], wv.y, p[c4 * 4 + 1]);
      p[c4 * 4 + 2] = fmaf(r[j], wv.z, p[c4 * 4 + 2]);
      p[c4 * 4 + 3] = fmaf(r[j], wv.w, p[c4 * 4 + 3]);
    }
  }

#pragma unroll
  for (int off = 32; off >= 16; off >>= 1)
#pragma unroll
    for (int i = 0; i < 16; ++i) p[i] += __shfl_xor(p[i], off, 64);

  if (lane < 16) {
#pragma unroll
    for (int i = 0; i < 16; ++i) red[wave][lane][i] = p[i];
  }
  if (lane < 16) {
    float sum = 0.f;
#pragma unroll
    for (int i = 0; i < 16; ++i) sum += red[wave][i][lane];
    h2[(size_t)node * NUM_CLASSES + lane] = (_Float16)sum;
  }
}

// ---------------------------------------------------------------------------
// Gather2 + softmax via MFMA. One wave per 16-dst tile. 64-edge chunks,
// depth-1 meta prefetch, two 32-row gathers + two MFMAs per iteration.
// dst-local from meta8 bits 16..19 (tiles are 16-aligned).
// ---------------------------------------------------------------------------
__global__ __launch_bounds__(256) void gather2_mfma_kernel(
    const _Float16* __restrict__ h2, const int* __restrict__ row_ptr,
    const uint2* __restrict__ meta8, float* __restrict__ out) {
  __shared__ _Float16 lds[4][16][72];  // per-wave slice
  const int wave = threadIdx.x >> 6;
  const int lane = threadIdx.x & 63;
  const int tile = blockIdx.x * 4 + wave;
  if (tile >= N_NODES / 16) return;
  const int t0 = tile * 16;
  const int beg = row_ptr[t0];
  const int end = row_ptr[t0 + 16];

  const int cls = lane & 15;   // class (N) / dst-local for A (M)
  const int kq = lane >> 4;    // k-octet
  const int erow = lane >> 1;  // staged edge 0..31
  const int part = lane & 1;   // class half for staging

  f32x4 acc = {0.f, 0.f, 0.f, 0.f};
  _Float16* myl = &lds[wave][0][0];

  if (beg < end) {
    const int last = end - 1;
    int e = beg + lane;
    uint2 m = meta8[(e <= last) ? e : last];
    float wv = (e <= last) ? __uint_as_float(m.y) : 0.f;

    for (int c0 = beg; c0 < end; c0 += 64) {
      // depth-1 prefetch of next chunk's meta
      uint2 mn = m;
      float wn = 0.f;
      const int c1 = c0 + 64;
      if (c1 < end) {
        const int en = c1 + lane;
        mn = meta8[(en <= last) ? en : last];
        wn = (en <= last) ? __uint_as_float(mn.y) : 0.f;
      }

      // stage 64 rows (two b128 gathers per lane, independent)
      const int se0 = __shfl((int)m.x, erow, 64) & 0xFFFF;
      const int se1 = __shfl((int)m.x, 32 + erow, 64) & 0xFFFF;
      const f16x8 r0 =
          *(const f16x8*)(h2 + (size_t)se0 * NUM_CLASSES + part * 8);
      const f16x8 r1 =
          *(const f16x8*)(h2 + (size_t)se1 * NUM_CLASSES + part * 8);

      // A-frags: Sel[m=dst-local][k=edge] = w_e * (dst_local_e == m)
      f16x8 a0, a1;
#pragma unroll
      for (int j = 0; j < 8; ++j) {
        const int ei = kq * 8 + j;
        const int p0 = __shfl((int)m.x, ei, 64);
        const float w0 = __shfl(wv, ei, 64);
        a0[j] = (((p0 >> 16) & 15) == cls) ? (_Float16)w0 : (_Float16)0.f;
        const int p1 = __shfl((int)m.x, 32 + ei, 64);
        const float w1 = __shfl(wv, 32 + ei, 64);
        a1[j] = (((p1 >> 16) & 15) == cls) ? (_Float16)w1 : (_Float16)0.f;
      }

      // transpose into wave-private LDS: [class][edge]
#pragma unroll
      for (int j = 0; j < 8; ++j) myl[(part * 8 + j) * 72 + erow] = r0[j];
#pragma unroll
      for (int j = 0; j < 8; ++j) myl[(part * 8 + j) * 72 + 32 + erow] = r1[j];

      // B-frags: B[k=edge][n=class] (contiguous b128 reads)
      const f16x8 b0 = *(const f16x8*)(myl + cls * 72 + kq * 8);
      const f16x8 b1 = *(const f16x8*)(myl + cls * 72 + 32 + kq * 8);

      acc = __builtin_amdgcn_mfma_f32_16x16x32_f16(a0, b0, acc, 0, 0, 0);
      acc = __builtin_amdgcn_mfma_f32_16x16x32_f16(a1, b1, acc, 0, 0, 0);

      m = mn;
      wv = wn;
    }
  }

  // softmax per dst (classes live across the quad's 16 lanes)
#pragma unroll
  for (int r = 0; r < 4; ++r) {
    const float a = acc[r];
    float mx = a;
#pragma unroll
    for (int off = 8; off >= 1; off >>= 1)
      mx = fmaxf(mx, __shfl_xor(mx, off, 16));
    const float ex = __expf(a - mx);
    float sm = ex;
#pragma unroll
    for (int off = 8; off >= 1; off >>= 1) sm += __shfl_xor(sm, off, 16);
    out[(size_t)(t0 + kq * 4 + r) * NUM_CLASSES + cls] = ex / sm;
  }
}

extern "C" void kernel_launch(void* const* d_in, const int* in_sizes, int n_in,
                              void* d_out, int out_size, void* d_ws,
                              size_t ws_size, hipStream_t stream) {
  const float* x = (const float*)d_in[0];
  const float* W1 = (const float*)d_in[1];
  const float* W2 = (const float*)d_in[2];
  const float* ew = (const float*)d_in[3];
  const int* esrc = (const int*)d_in[4];
  const int* edst = (const int*)d_in[5];
  float* out = (float*)d_out;

  _Float16* xw1 = (_Float16*)d_ws;                               // 25.6 MB
  _Float16* h2 = xw1 + (size_t)N_NODES * FILTERS;                // 1.6 MB
  int* row_ptr = (int*)(h2 + (size_t)N_NODES * NUM_CLASSES);     // 50001
  int* deg8 = row_ptr + (N_NODES + 1);                           // 8*50000
  int* cursor8 = deg8 + NXCD * N_NODES;                          // 8*50000
  uint2* meta8 = (uint2*)(((uintptr_t)(cursor8 + NXCD * N_NODES) + 15) &
                          ~(uintptr_t)15);                       // 12.8 MB
  __bf16* w1th = (__bf16*)(meta8 + N_EDGES);
  __bf16* w1tl = w1th + D_FEAT * FILTERS;
  int* bsum = (int*)(w1tl + D_FEAT * FILTERS);                   // 256 ints

  hipMemsetAsync(deg8, 0, NXCD * N_NODES * sizeof(int), stream);
  hist8_kernel<<<(N_EDGES + 255) / 256, 256, 0, stream>>>(edst, deg8, W1,
                                                          w1th, w1tl);
  scan_blocks_kernel<<<SCAN_NB, 256, 0, stream>>>(deg8, row_ptr, bsum);
  scan_add_cursor8_kernel<<<SCAN_NB, 256, 0, stream>>>(row_ptr, bsum, deg8,
                                                       cursor8);

  // gemm1 (782 blocks) || fill (6250 blocks) in one launch
  gemm1_fill_kernel<<<G1_BLOCKS + (N_EDGES + 255) / 256, 256, 0, stream>>>(
      x, w1th, w1tl, xw1, esrc, edst, ew, cursor8, meta8);

  gather1_gemm2_kernel<<<N_NODES / 4, 256, 0, stream>>>(xw1, row_ptr, meta8,
                                                        W2, h2);

  gather2_mfma_kernel<<<(N_NODES / 16 + 3) / 4, 256, 0, stream>>>(h2, row_ptr,
                                                                  meta8, out);
}